// Round 7
// baseline (1469.319 us; speedup 1.0000x reference)
//
#include <hip/hip_runtime.h>
#include <hip/hip_bf16.h>
#include <math.h>

#define B_ 32
#define S_ 64
#define T_ 64
#define V_ 32000
#define E_ 512
#define H_ 1024

typedef __attribute__((ext_vector_type(8))) short short8;
typedef __attribute__((ext_vector_type(4))) float f32x4;

static __device__ __forceinline__ unsigned short f2bf(float f) {
  union { float f; unsigned u; } c; c.f = f;
  unsigned r = (c.u + 0x7fffu + ((c.u >> 16) & 1u)) >> 16;  // RNE
  return (unsigned short)r;
}

// async global->LDS, 16B per lane. LDS dest = wave-uniform base + lane*16.
static __device__ __forceinline__ void gload_lds16(const void* g, void* l) {
  __builtin_amdgcn_global_load_lds(
      (const __attribute__((address_space(1))) void*)g,
      (__attribute__((address_space(3))) void*)l, 16, 0, 0);
}

// ---------- gather embedding rows (fp32, exact) ----------
__global__ __launch_bounds__(128)
void gather_f32(const int* __restrict__ idx, const float* __restrict__ emb,
                float* __restrict__ dst) {
  int r = blockIdx.x;
  int tid = threadIdx.x;
  int tok = idx[r];
  float4 v = *(const float4*)(emb + (size_t)tok * E_ + tid * 4);
  *(float4*)(dst + (size_t)r * E_ + tid * 4) = v;
}

// ---------- f64-accumulate GEMM: C[M,N](f32) = A[M,K](f32) @ B[K,N](f32) + bias ----------
__global__ __launch_bounds__(256)
void dgemm_bias(const float* __restrict__ A, const float* __restrict__ B,
                const float* __restrict__ bias, float* __restrict__ C,
                int M, int N, int K) {
  __shared__ float As[32][65];  // [k][m], padded
  __shared__ float Bs[32][64];  // [k][n]
  const int nbm = M >> 6;
  const int bm = blockIdx.x % nbm;
  const int bn = blockIdx.x / nbm;
  const int tid = threadIdx.x;
  const int tr = tid >> 4, tc = tid & 15;
  double acc[4][4] = {};

  for (int kt = 0; kt < K; kt += 32) {
    {
      int arow = tid >> 3, acol = (tid & 7) * 4;
#pragma unroll
      for (int p = 0; p < 2; ++p) {
        int r = arow + p * 32;
        float4 v = *(const float4*)(A + (size_t)(bm * 64 + r) * K + kt + acol);
        As[acol + 0][r] = v.x; As[acol + 1][r] = v.y;
        As[acol + 2][r] = v.z; As[acol + 3][r] = v.w;
      }
      int brow = tid >> 4, bcol = (tid & 15) * 4;
#pragma unroll
      for (int p = 0; p < 2; ++p) {
        int r = brow + p * 16;
        float4 v = *(const float4*)(B + (size_t)(kt + r) * N + bn * 64 + bcol);
        *(float4*)(&Bs[r][bcol]) = v;
      }
    }
    __syncthreads();
#pragma unroll
    for (int k = 0; k < 32; ++k) {
      double a[4], b[4];
#pragma unroll
      for (int i = 0; i < 4; ++i) a[i] = (double)As[k][tr * 4 + i];
#pragma unroll
      for (int j = 0; j < 4; ++j) b[j] = (double)Bs[k][tc * 4 + j];
#pragma unroll
      for (int i = 0; i < 4; ++i)
#pragma unroll
        for (int j = 0; j < 4; ++j) acc[i][j] = fma(a[i], b[j], acc[i][j]);
    }
    __syncthreads();
  }
#pragma unroll
  for (int i = 0; i < 4; ++i) {
    int gm = bm * 64 + tr * 4 + i;
    int gn = bn * 64 + tc * 4;
    float4 o;
    o.x = (float)(acc[i][0] + (double)bias[gn + 0]);
    o.y = (float)(acc[i][1] + (double)bias[gn + 1]);
    o.z = (float)(acc[i][2] + (double)bias[gn + 2]);
    o.w = (float)(acc[i][3] + (double)bias[gn + 3]);
    *(float4*)(C + (size_t)gm * N + gn) = o;
  }
}

// ---------- transpose fp32 [K][N] -> fp32 [N][K] ----------
__global__ __launch_bounds__(256)
void transpose_f32(const float* __restrict__ W, float* __restrict__ WT,
                   int K, int N) {
  __shared__ float t[64][65];
  int k0 = blockIdx.x * 64;
  int n0 = blockIdx.y * 64;
  int tid = threadIdx.x;
  int r = tid >> 4, c4 = tid & 15;
#pragma unroll
  for (int i = 0; i < 4; ++i) {
    int row = r + i * 16;
    float4 v = *(const float4*)(W + (size_t)(k0 + row) * N + n0 + c4 * 4);
    t[row][c4 * 4 + 0] = v.x; t[row][c4 * 4 + 1] = v.y;
    t[row][c4 * 4 + 2] = v.z; t[row][c4 * 4 + 3] = v.w;
  }
  __syncthreads();
#pragma unroll
  for (int i = 0; i < 4; ++i) {
    int n = r + i * 16;
    float4 o;
    o.x = t[c4 * 4 + 0][n]; o.y = t[c4 * 4 + 1][n];
    o.z = t[c4 * 4 + 2][n]; o.w = t[c4 * 4 + 3][n];
    *(float4*)(WT + (size_t)(n0 + n) * K + k0 + c4 * 4) = o;
  }
}

// ---------- transpose fp32 [K][N] -> bf16 [N][K] ----------
__global__ __launch_bounds__(256)
void transpose_bf16(const float* __restrict__ W, unsigned short* __restrict__ WT,
                    int K, int N) {
  __shared__ float t[64][65];
  int k0 = blockIdx.x * 64;
  int n0 = blockIdx.y * 64;
  int tid = threadIdx.x;
  int r = tid >> 4, c4 = tid & 15;
#pragma unroll
  for (int i = 0; i < 4; ++i) {
    int row = r + i * 16;
    float4 v = *(const float4*)(W + (size_t)(k0 + row) * N + n0 + c4 * 4);
    t[row][c4 * 4 + 0] = v.x; t[row][c4 * 4 + 1] = v.y;
    t[row][c4 * 4 + 2] = v.z; t[row][c4 * 4 + 3] = v.w;
  }
  __syncthreads();
#pragma unroll
  for (int i = 0; i < 4; ++i) {
    int n = r + i * 16;
    ushort4 o;
    o.x = f2bf(t[c4 * 4 + 0][n]); o.y = f2bf(t[c4 * 4 + 1][n]);
    o.z = f2bf(t[c4 * 4 + 2][n]); o.w = f2bf(t[c4 * 4 + 3][n]);
    *(ushort4*)(WT + (size_t)(n0 + n) * K + k0 + c4 * 4) = o;
  }
}

// ---------- bf16 MFMA GEMM: C[M,N] = A[M,K] * BT[N,K]^T + bias ----------
// 128x128 tile. Staging via global_load_lds: LINEAR LDS dest + pre-swizzled
// global source; reads use the XOR swizzle (granule gi holds
// A[gi>>3][(gi&7)^(row&7)] -> read addr kc^(row&7) yields column kc).
// XCD-aware block swizzle + NT C-stores.
__global__ __launch_bounds__(256)
void gemm_bt_swap(const unsigned short* __restrict__ A, const unsigned short* __restrict__ BT,
                  const float* __restrict__ bias, float* __restrict__ C,
                  int M, int N, int K) {
  __shared__ unsigned short As[128 * 64];
  __shared__ unsigned short Bs[128 * 64];
  const int nbm = M >> 7;
  int idx = blockIdx.x;
  const int cpx = gridDim.x >> 3;
  idx = (idx & 7) * cpx + (idx >> 3);
  const int bm = idx % nbm;
  const int bn = idx / nbm;
  const int tid = threadIdx.x;
  const int lane = tid & 63;
  const int w4 = tid >> 6;
  const int wr = w4 >> 1;
  const int wc = w4 & 1;

  f32x4 acc[4][4] = {};

  for (int kt = 0; kt < K; kt += 64) {
#pragma unroll
    for (int p = 0; p < 4; ++p) {
      int gi = w4 * 256 + p * 64 + lane;     // granule index 0..1023
      int row = gi >> 3;
      int col8 = (gi & 7) ^ (row & 7);       // inverse swizzle on the source
      gload_lds16(A + (size_t)(bm * 128 + row) * K + kt + col8 * 8,
                  As + (w4 * 256 + p * 64) * 8);
      gload_lds16(BT + (size_t)(bn * 128 + row) * K + kt + col8 * 8,
                  Bs + (w4 * 256 + p * 64) * 8);
    }
    __syncthreads();
#pragma unroll
    for (int kk = 0; kk < 64; kk += 32) {
      int kc = (kk + ((lane >> 4) << 3)) >> 3;
      short8 af[4], bfr[4];
#pragma unroll
      for (int mi = 0; mi < 4; ++mi) {
        int row = wr * 64 + mi * 16 + (lane & 15);
        af[mi] = *(const short8*)(As + row * 64 + ((kc ^ (row & 7)) << 3));
      }
#pragma unroll
      for (int ni = 0; ni < 4; ++ni) {
        int row = wc * 64 + ni * 16 + (lane & 15);
        bfr[ni] = *(const short8*)(Bs + row * 64 + ((kc ^ (row & 7)) << 3));
      }
#pragma unroll
      for (int mi = 0; mi < 4; ++mi)
#pragma unroll
        for (int ni = 0; ni < 4; ++ni)
          acc[mi][ni] = __builtin_amdgcn_mfma_f32_16x16x32_bf16(
              af[mi], bfr[ni], acc[mi][ni], 0, 0, 0);
    }
    __syncthreads();
  }

  const int cq = (lane >> 4) << 2;
  const int cn = lane & 15;
#pragma unroll
  for (int mi = 0; mi < 4; ++mi) {
#pragma unroll
    for (int ni = 0; ni < 4; ++ni) {
      int gn = bn * 128 + wc * 64 + ni * 16 + cn;
      float bv = bias[gn];
#pragma unroll
      for (int q = 0; q < 4; ++q) {
        int gm = bm * 128 + wr * 64 + mi * 16 + cq + q;
        int b = gm & (B_ - 1);
        int t = gm >> 5;
        __builtin_nontemporal_store(acc[mi][ni][q] + bv,
                                    &C[((size_t)b * T_ + t) * N + gn]);
      }
    }
  }
}

// ---------- RNN step v4: h_out = tanh(x + h_in @ Whh + bhh) ----------
// Grid 256 x 512. W slice [4][1024] staged via global_load_lds (linear).
// All h float4 loads + x/bias tail loads issued BEFORE the barrier so W, h
// and x latencies overlap. Rb=4 x Rj=4 register tile, 64-way k-split,
// acc-halving pair-swap reduction (17 f64 shfls).
__global__ __launch_bounds__(512)
void rnn_scan_step4(const float* __restrict__ h_in, const float* __restrict__ x,
                    int s, const float* __restrict__ WT,
                    const float* __restrict__ bhh, float* __restrict__ h_out,
                    unsigned short* __restrict__ hs_bf16) {
  __shared__ float wl[4 * 1024];  // 16 KB
  const int jbase = blockIdx.x * 4;
  const int tid = threadIdx.x;
  const int wv8 = tid >> 6;   // wave 0..7
  const int l = tid & 63;
  const int bt = wv8;         // 8 b-tiles of 4 rows
  const int ks = l;           // k-split lane

  // ---- issue W staging (async, 2 gload_lds per wave) ----
  const float* wsrc = WT + (size_t)jbase * 1024;
#pragma unroll
  for (int p = 0; p < 2; ++p) {
    int gb0 = wv8 * 128 + p * 64;           // wave-uniform granule base
    gload_lds16(wsrc + (size_t)(gb0 + l) * 4, wl + (size_t)gb0 * 4);
  }

  // ---- issue output-tail loads early ----
  const int a = 8 * (ks & 1) + 4 * ((ks >> 1) & 1) + 2 * ((ks >> 2) & 1) +
                ((ks >> 3) & 1);
  const int gb = bt * 4 + (a >> 2);
  const int gj = jbase + (a & 3);
  float xv = x[((size_t)gb * 64 + s) * 1024 + gj];
  float bj = bhh[gj];

  // ---- issue all 16 h loads (overlap with W staging) ----
  float4 hv[4][4];
#pragma unroll
  for (int i = 0; i < 4; ++i) {
    int g = ks + 64 * i;
#pragma unroll
    for (int bi = 0; bi < 4; ++bi)
      hv[i][bi] = *(const float4*)(h_in + (bt * 4 + bi) * 1024 + g * 4);
  }

  __syncthreads();  // drains gload_lds (vmcnt) + orders LDS

  double acc[4][4];
#pragma unroll
  for (int bi = 0; bi < 4; ++bi)
#pragma unroll
    for (int ji = 0; ji < 4; ++ji) acc[bi][ji] = 0.;

#pragma unroll
  for (int i = 0; i < 4; ++i) {
    int g = ks + 64 * i;
    float4 wvv[4];
#pragma unroll
    for (int ji = 0; ji < 4; ++ji)
      wvv[ji] = *(const float4*)(wl + ji * 1024 + g * 4);
#pragma unroll
    for (int bi = 0; bi < 4; ++bi)
#pragma unroll
      for (int ji = 0; ji < 4; ++ji) {
        acc[bi][ji] = fma((double)hv[i][bi].x, (double)wvv[ji].x, acc[bi][ji]);
        acc[bi][ji] = fma((double)hv[i][bi].y, (double)wvv[ji].y, acc[bi][ji]);
        acc[bi][ji] = fma((double)hv[i][bi].z, (double)wvv[ji].z, acc[bi][ji]);
        acc[bi][ji] = fma((double)hv[i][bi].w, (double)wvv[ji].w, acc[bi][ji]);
      }
  }

  // acc-halving pair-swap reduction; final owner a = 8b0+4b1+2b2+1b3.
  double r8[8], r4[4], r2[2], r1;
#pragma unroll
  for (int aa = 0; aa < 8; ++aa) {
    double send = (l & 1) ? acc[aa >> 2][aa & 3] : acc[(aa + 8) >> 2][(aa + 8) & 3];
    double mine = (l & 1) ? acc[(aa + 8) >> 2][(aa + 8) & 3] : acc[aa >> 2][aa & 3];
    r8[aa] = mine + __shfl_xor(send, 1);
  }
#pragma unroll
  for (int aa = 0; aa < 4; ++aa) {
    double send = (l & 2) ? r8[aa] : r8[aa + 4];
    double mine = (l & 2) ? r8[aa + 4] : r8[aa];
    r4[aa] = mine + __shfl_xor(send, 2);
  }
#pragma unroll
  for (int aa = 0; aa < 2; ++aa) {
    double send = (l & 4) ? r4[aa] : r4[aa + 2];
    double mine = (l & 4) ? r4[aa + 2] : r4[aa];
    r2[aa] = mine + __shfl_xor(send, 4);
  }
  {
    double send = (l & 8) ? r2[0] : r2[1];
    double mine = (l & 8) ? r2[1] : r2[0];
    r1 = mine + __shfl_xor(send, 8);
  }
  r1 += __shfl_xor(r1, 16);
  r1 += __shfl_xor(r1, 32);

  if (l < 16) {
    double v = r1 + (double)xv + (double)bj;
    double h = tanh(v);
    h_out[gb * 1024 + gj] = (float)h;
    if (hs_bf16) hs_bf16[(size_t)s * (B_ * H_) + gb * 1024 + gj] = f2bf((float)h);
  }
}

// ---------- in-place log-softmax over rows of 32000 ----------
__global__ __launch_bounds__(512)
void log_softmax_rows(float* __restrict__ out) {
  float* row = out + (size_t)blockIdx.x * V_;
  const int tid = threadIdx.x;
  float m = -INFINITY, s = 0.f;
  for (int i = tid; i < V_ / 4; i += 512) {
    float4 v = *(const float4*)(row + i * 4);
    float mx = fmaxf(fmaxf(v.x, v.y), fmaxf(v.z, v.w));
    if (mx > m) { s *= __expf(m - mx); m = mx; }
    s += __expf(v.x - m) + __expf(v.y - m) + __expf(v.z - m) + __expf(v.w - m);
  }
#pragma unroll
  for (int o = 32; o; o >>= 1) {
    float mo = __shfl_xor(m, o);
    float so = __shfl_xor(s, o);
    float mn = fmaxf(m, mo);
    s = s * __expf(m - mn) + so * __expf(mo - mn);
    m = mn;
  }
  __shared__ float wm[8], wsv[8];
  int wv = tid >> 6;
  if ((tid & 63) == 0) { wm[wv] = m; wsv[wv] = s; }
  __syncthreads();
  float M = wm[0];
#pragma unroll
  for (int i = 1; i < 8; ++i) M = fmaxf(M, wm[i]);
  float Ssum = 0.f;
#pragma unroll
  for (int i = 0; i < 8; ++i) Ssum += wsv[i] * __expf(wm[i] - M);
  float L = M + logf(Ssum);
  for (int i = tid; i < V_ / 4; i += 512) {
    float4 v = *(const float4*)(row + i * 4);
    v.x -= L; v.y -= L; v.z -= L; v.w -= L;
    __builtin_nontemporal_store(v.x, &row[i * 4 + 0]);
    __builtin_nontemporal_store(v.y, &row[i * 4 + 1]);
    __builtin_nontemporal_store(v.z, &row[i * 4 + 2]);
    __builtin_nontemporal_store(v.w, &row[i * 4 + 3]);
  }
}

extern "C" void kernel_launch(void* const* d_in, const int* in_sizes, int n_in,
                              void* d_out, int out_size, void* d_ws, size_t ws_size,
                              hipStream_t stream) {
  const int*   src  = (const int*)  d_in[0];
  const int*   tgt  = (const int*)  d_in[1];
  const float* encE = (const float*)d_in[2];
  const float* decE = (const float*)d_in[3];
  const float* WihE = (const float*)d_in[4];
  const float* bihE = (const float*)d_in[5];
  const float* WhhE = (const float*)d_in[6];
  const float* bhhE = (const float*)d_in[7];
  const float* WihD = (const float*)d_in[8];
  const float* bihD = (const float*)d_in[9];
  const float* WhhD = (const float*)d_in[10];
  const float* bhhD = (const float*)d_in[11];
  const float* Wout = (const float*)d_in[12];
  const float* bout = (const float*)d_in[13];
  float* out = (float*)d_out;

  char* w = (char*)d_ws;
  float* x_e = (float*)w;                      w += (size_t)2048 * 1024 * 4;
  float* x_d = (float*)w;                      w += (size_t)2048 * 1024 * 4;
  float* h0  = (float*)w;                      w += 32 * 1024 * 4;
  float* h1  = (float*)w;                      w += 32 * 1024 * 4;
  float* WhhTe = (float*)w;                    w += (size_t)1024 * 1024 * 4;
  float* WhhTd = (float*)w;                    w += (size_t)1024 * 1024 * 4;
  float* AembF = (float*)w;                    w += (size_t)2048 * 512 * 4;
  unsigned short* hsb   = (unsigned short*)w;  w += (size_t)2048 * 1024 * 2;
  unsigned short* WoutT = (unsigned short*)w;  w += (size_t)V_ * 1024 * 2;

  // Input projections (f64-exact accumulate, f32 storage)
  gather_f32<<<B_ * S_, 128, 0, stream>>>(src, encE, AembF);
  dgemm_bias<<<(2048 / 64) * (H_ / 64), 256, 0, stream>>>(AembF, WihE, bihE, x_e,
                                                          2048, H_, E_);
  gather_f32<<<B_ * T_, 128, 0, stream>>>(tgt, decE, AembF);
  dgemm_bias<<<(2048 / 64) * (H_ / 64), 256, 0, stream>>>(AembF, WihD, bihD, x_d,
                                                          2048, H_, E_);

  // Pre-transpose recurrence weights: WhhT[j][k]
  transpose_f32<<<dim3(H_ / 64, H_ / 64), 256, 0, stream>>>(WhhE, WhhTe, H_, H_);
  transpose_f32<<<dim3(H_ / 64, H_ / 64), 256, 0, stream>>>(WhhD, WhhTd, H_, H_);

  // Encoder scan
  hipMemsetAsync(h0, 0, 32 * 1024 * 4, stream);
  float* hc = h0;
  float* hn = h1;
  for (int s = 0; s < S_; ++s) {
    rnn_scan_step4<<<256, 512, 0, stream>>>(hc, x_e, s, WhhTe, bhhE, hn,
                                            (unsigned short*)nullptr);
    float* tmp = hc; hc = hn; hn = tmp;
  }
  // Decoder scan, emitting hs rows (bf16, non-feedback) at row t*B + b
  for (int t = 0; t < T_; ++t) {
    rnn_scan_step4<<<256, 512, 0, stream>>>(hc, x_d, t, WhhTd, bhhD, hn, hsb);
    float* tmp = hc; hc = hn; hn = tmp;
  }

  // Logits: out[b][t][:] = hs[t*B+b] @ Wout + bout  (bf16 MFMA, raw logits)
  transpose_bf16<<<dim3(H_ / 64, V_ / 64), 256, 0, stream>>>(Wout, WoutT, H_, V_);
  gemm_bt_swap<<<(2048 / 128) * (V_ / 128), 256, 0, stream>>>(hsb, WoutT, bout, out,
                                                              2048, V_, H_);
  // In-place log-softmax
  log_softmax_rows<<<B_ * T_, 512, 0, stream>>>(out);
}